// Round 16
// baseline (323.035 us; speedup 1.0000x reference)
//
#include <hip/hip_runtime.h>

// 3-layer LSTM (B=1024, T=512, H=64), f16 MFMA, fp32 cell state.
// grid = 256 blocks x 4 batches; 768 threads = 12 waves = 3 layer-teams x 4.
// R16 = R14 (champion, 295.7us) + ONE change: quad-rcp batched activation
// (1 rcp of the 4-gate product + 9 muls replaces 4 rcps) -> 3 fewer
// quarter-rate trans ops per cell on the serialized VALU/trans pipe.
// med3 clamps +-30 keep the product finite (exp2(30)^4 = 1e36 < f32 max);
// identical math was validated in R7 (same absmax 9.77e-4).
//
// Team L computes layer L at t = s - L (skewed pipeline), ONE barrier/step.
// A-frag reads use slot = l15>>2 (4-way same-address broadcast) so
// acc[tt][0] on lane (l4,l15) IS the preact of cell (batch=l4, unit=w*16+l15).
// Weights & biases PRE-SCALED by -log2e (g: -2log2e).
// mfma_f32_16x16x32_f16: A row = lane&15, k-chunk = lane>>4; D col = lane&15,
// D row = (lane>>4)*4+reg -- layout verified R2-R15.

typedef __attribute__((ext_vector_type(8))) _Float16 half8;
typedef __attribute__((ext_vector_type(4))) _Float16 half4;
typedef __attribute__((ext_vector_type(4))) float floatx4;

static constexpr int T_STEPS = 512;

#define NL2E  (-1.4426950408889634f)   // -log2(e)
#define N2L2E (-2.8853900817779268f)   // -2*log2(e)

// LDS: "cr" rows of 256B = [16 slots][16B]; slot ^= (cr&1)<<2.
// CR_X  : [2 buf][4 chunks]  (x frags, k=0..31, 24 real + 8 zero pad)
// CR_Hl : [2 buf][8 chunks]  (h frags, 64 units); slots 0..3 = batches.
#define CR_X   0
#define CR_H0  8
#define CR_H1  24
#define CR_H2  40
#define CR_TOT 56
#define SM_BYTES (CR_TOT * 256)        // 14336 B

__device__ __forceinline__ int lds_off(int cr, int slot) {
    return (cr * 16 + (slot ^ ((cr & 1) << 2))) * 16;
}

__device__ __forceinline__ floatx4 mfma16(half8 a, half8 b, floatx4 c) {
    return __builtin_amdgcn_mfma_f32_16x16x32_f16(a, b, c, 0, 0, 0);
}

__device__ __forceinline__ half8 cvt8s(const float* src, float s) {
    float4 v0 = *(const float4*)(src);
    float4 v1 = *(const float4*)(src + 4);
    half8 h;
    h[0] = (_Float16)(v0.x * s); h[1] = (_Float16)(v0.y * s);
    h[2] = (_Float16)(v0.z * s); h[3] = (_Float16)(v0.w * s);
    h[4] = (_Float16)(v1.x * s); h[5] = (_Float16)(v1.y * s);
    h[6] = (_Float16)(v1.z * s); h[7] = (_Float16)(v1.w * s);
    return h;
}

__global__ __launch_bounds__(768, 3) void lstm3_v16(
    const float* __restrict__ x,
    const float* __restrict__ w_ih0, const float* __restrict__ w_hh0,
    const float* __restrict__ b_ih0, const float* __restrict__ b_hh0,
    const float* __restrict__ w_ih1, const float* __restrict__ w_hh1,
    const float* __restrict__ b_ih1, const float* __restrict__ b_hh1,
    const float* __restrict__ w_ih2, const float* __restrict__ w_hh2,
    const float* __restrict__ b_ih2, const float* __restrict__ b_hh2,
    const float* __restrict__ w_lin, const float* __restrict__ b_lin,
    float* __restrict__ out)
{
    __shared__ __align__(16) char sm[SM_BYTES];

    const int tid  = threadIdx.x;
    const int lane = tid & 63;
    const int wave = tid >> 6;       // 0..11
    const int L    = wave >> 2;      // layer team 0..2
    const int w    = wave & 3;       // unit group within team
    const int l15  = lane & 15;
    const int l4   = lane >> 4;      // = this lane's BATCH
    const int b0   = blockIdx.x * 4; // global batch base (4 per block)
    const int u    = w * 16 + l15;   // this lane's hidden unit
    const int sl   = l15 >> 2;       // broadcast A slot

    // ---- zero x + h frag regions ----
    for (int i = tid; i < CR_TOT * 16; i += 768)
        *(floatx4*)(&sm[i * 16]) = floatx4{0.f, 0.f, 0.f, 0.f};

    // ---- per-team parameter pointers ----
    const float* wi = (L == 0) ? w_ih0 : (L == 1 ? w_ih1 : w_ih2);
    const float* wh = (L == 0) ? w_hh0 : (L == 1 ? w_hh1 : w_hh2);
    const float* bi = (L == 0) ? b_ih0 : (L == 1 ? b_ih1 : b_ih2);
    const float* bh = (L == 0) ? b_hh0 : (L == 1 ? b_hh1 : b_hh2);
    const int hbase = (L == 0) ? CR_H0 : (L == 1 ? CR_H1 : CR_H2);
    const int pbase = (L == 0) ? CR_X  : (L == 1 ? CR_H0 : CR_H1);

    // ---- register-resident B frags (weights), PRE-SCALED by -log2e ----
    half8 wf[4][4];
#pragma unroll
    for (int tt = 0; tt < 4; ++tt) {
        const int g = tt * 64 + u;
        const float sc = (tt == 2) ? N2L2E : NL2E;
        if (L == 0) {
            half8 z;
#pragma unroll
            for (int j = 0; j < 8; ++j) z[j] = (_Float16)0.f;
            wf[tt][0] = (l4 < 3) ? cvt8s(w_ih0 + g * 24 + l4 * 8, sc) : z;
            wf[tt][1] = cvt8s(w_hh0 + g * 64 + l4 * 8, sc);
            wf[tt][2] = cvt8s(w_hh0 + g * 64 + 32 + l4 * 8, sc);
            wf[tt][3] = z;   // unused
        } else {
            wf[tt][0] = cvt8s(wi + g * 64 + l4 * 8, sc);
            wf[tt][1] = cvt8s(wi + g * 64 + 32 + l4 * 8, sc);
            wf[tt][2] = cvt8s(wh + g * 64 + l4 * 8, sc);
            wf[tt][3] = cvt8s(wh + g * 64 + 32 + l4 * 8, sc);
        }
    }

    // ---- pre-scaled bias as MFMA C-input (same for all 4 acc rows) ----
    floatx4 bv[4];
#pragma unroll
    for (int tt = 0; tt < 4; ++tt) {
        const float sc = (tt == 2) ? N2L2E : NL2E;
        float b = sc * (bi[tt * 64 + u] + bh[tt * 64 + u]);
        bv[tt][0] = b; bv[tt][1] = b; bv[tt][2] = b; bv[tt][3] = b;
    }
    float cst = 0.0f;    // fp32 cell state of (batch l4, unit u, layer L)

    // ---- precomputed LDS byte addresses, both parities ----
    int ra0[4], ra1[4];
    if (L == 0) {
        ra0[0] = lds_off(CR_X + 0 + l4, sl);
        ra0[1] = lds_off(CR_H0 + 8 + l4, sl);
        ra0[2] = lds_off(CR_H0 + 12 + l4, sl);
        ra0[3] = 0;
        ra1[0] = lds_off(CR_X + 4 + l4, sl);
        ra1[1] = lds_off(CR_H0 + 0 + l4, sl);
        ra1[2] = lds_off(CR_H0 + 4 + l4, sl);
        ra1[3] = 0;
    } else {
        ra0[0] = lds_off(pbase + 0 + l4, sl);
        ra0[1] = lds_off(pbase + 4 + l4, sl);
        ra0[2] = lds_off(hbase + 8 + l4, sl);
        ra0[3] = lds_off(hbase + 12 + l4, sl);
        ra1[0] = lds_off(pbase + 8 + l4, sl);
        ra1[1] = lds_off(pbase + 12 + l4, sl);
        ra1[2] = lds_off(hbase + 0 + l4, sl);
        ra1[3] = lds_off(hbase + 4 + l4, sl);
    }
    const int wr0 = lds_off(hbase + 0 + (u >> 3), l4) + (u & 7) * 2;
    const int wr1 = lds_off(hbase + 8 + (u >> 3), l4) + (u & 7) * 2;

    // parity selects (loop-invariant, hoisted): even-s body has par = L&1
    const int Lodd = L & 1;
    const int eA0 = Lodd ? ra1[0] : ra0[0], eA1 = Lodd ? ra1[1] : ra0[1];
    const int eA2 = Lodd ? ra1[2] : ra0[2], eA3 = Lodd ? ra1[3] : ra0[3];
    const int oA0 = Lodd ? ra0[0] : ra1[0], oA1 = Lodd ? ra0[1] : ra1[1];
    const int oA2 = Lodd ? ra0[2] : ra1[2], oA3 = Lodd ? ra0[3] : ra1[3];
    const int eWr = Lodd ? wr1 : wr0, oWr = Lodd ? wr0 : wr1;

    // ---- x staging: thread tid<24 owns (batch xb, float4 xf) ----
    const int xb = tid / 6, xf = tid % 6;
    const int xw0 = lds_off(CR_X + 0 + (xf >> 1), xb) + (xf & 1) * 8;
    const int xw1 = lds_off(CR_X + 4 + (xf >> 1), xb) + (xf & 1) * 8;
    const float* xg = x + ((long)(b0 + xb) * T_STEPS + 1) * 24 + xf * 4;
    if (tid < 24) {
        float4 v = *(const float4*)(x + ((long)(b0 + xb) * T_STEPS + 0) * 24 + xf * 4);
        half4 hv; hv[0] = (_Float16)v.x; hv[1] = (_Float16)v.y;
                  hv[2] = (_Float16)v.z; hv[3] = (_Float16)v.w;
        *(half4*)(&sm[xw0]) = hv;
    }
    __syncthreads();

    auto body = [&](int s, int A0, int A1r, int A2r, int A3r, int WR, int XW) {
        const int t = s - L;
        const bool active = ((unsigned)t < (unsigned)T_STEPS);
        float4 xpre;
        const bool do_x = (tid < 24) && (s + 1 < T_STEPS);
        if (do_x) xpre = *(const float4*)xg;

        if (active) {
            floatx4 acc[4];
            __builtin_amdgcn_s_setprio(1);
            if (L == 0) {
                half8 aX  = *(const half8*)(&sm[A0]);
                half8 aP0 = *(const half8*)(&sm[A1r]);
                half8 aP1 = *(const half8*)(&sm[A2r]);
#pragma unroll
                for (int tt = 0; tt < 4; ++tt) {
                    acc[tt] = mfma16(aX,  wf[tt][0], bv[tt]);
                    acc[tt] = mfma16(aP0, wf[tt][1], acc[tt]);
                    acc[tt] = mfma16(aP1, wf[tt][2], acc[tt]);
                }
            } else {
                half8 aI0 = *(const half8*)(&sm[A0]);
                half8 aI1 = *(const half8*)(&sm[A1r]);
                half8 aO0 = *(const half8*)(&sm[A2r]);
                half8 aO1 = *(const half8*)(&sm[A3r]);
#pragma unroll
                for (int tt = 0; tt < 4; ++tt) {
                    acc[tt] = mfma16(aI0, wf[tt][0], bv[tt]);
                    acc[tt] = mfma16(aI1, wf[tt][1], acc[tt]);
                    acc[tt] = mfma16(aO0, wf[tt][2], acc[tt]);
                    acc[tt] = mfma16(aO1, wf[tt][3], acc[tt]);
                }
            }
            __builtin_amdgcn_s_setprio(0);

            // activation: 1 cell/lane; acc = -(preact)*log2e (g: -2log2e).
            // quad-rcp: one rcp of the 4-gate product replaces four rcps.
            float c0 = __builtin_amdgcn_fmed3f(acc[0][0], -30.f, 30.f);
            float c1 = __builtin_amdgcn_fmed3f(acc[1][0], -30.f, 30.f);
            float c2 = __builtin_amdgcn_fmed3f(acc[2][0], -30.f, 30.f);
            float c3 = __builtin_amdgcn_fmed3f(acc[3][0], -30.f, 30.f);
            float A1 = 1.f + __builtin_amdgcn_exp2f(c0);
            float B1 = 1.f + __builtin_amdgcn_exp2f(c1);
            float C1 = 1.f + __builtin_amdgcn_exp2f(c2);
            float D1 = 1.f + __builtin_amdgcn_exp2f(c3);
            float p = A1 * B1, q = C1 * D1;
            float r = __builtin_amdgcn_rcpf(p * q);
            float ip = r * q, iq = r * p;
            float ig = ip * B1;            // 1/A1 = sigmoid(i)
            float fg = ip * A1;            // 1/B1 = sigmoid(f)
            float sg = iq * D1;            // 1/C1 = sigmoid(2g)
            float og = iq * C1;            // 1/D1 = sigmoid(o)
            float gg = fmaf(2.f, sg, -1.f);                 // tanh(g)
            cst = fmaf(fg, cst, ig * gg);
            float et = __builtin_amdgcn_exp2f(cst * N2L2E);
            float th = fmaf(2.f, __builtin_amdgcn_rcpf(1.f + et), -1.f);
            float hv = og * th;
            *(_Float16*)(&sm[WR]) = (_Float16)hv;
        }
        if (do_x) {
            half4 hv; hv[0] = (_Float16)xpre.x; hv[1] = (_Float16)xpre.y;
                      hv[2] = (_Float16)xpre.z; hv[3] = (_Float16)xpre.w;
            *(half4*)(&sm[XW]) = hv;
        }
        xg += 24;
        __syncthreads();
    };

    for (int s = 0; s < T_STEPS + 2; s += 2) {
        body(s,     eA0, eA1, eA2, eA3, eWr, xw1);   // writes x(s+1) -> buf 1
        body(s + 1, oA0, oA1, oA2, oA3, oWr, xw0);   // writes x(s+2) -> buf 0
    }

    // ---- final linear: out[b,o] = h2(511) . w_lin[o,:] + b_lin[o] ----
    if (tid < 16) {
        const int bb = tid >> 2, o = tid & 3;
        const int hb = CR_H2 + ((T_STEPS - 1) & 1) * 8;
        float acc = b_lin[o];
#pragma unroll
        for (int k = 0; k < 64; ++k) {
            _Float16 hv = *(const _Float16*)(&sm[lds_off(hb + (k >> 3), bb) + (k & 7) * 2]);
            acc = fmaf((float)hv, w_lin[o * 64 + k], acc);
        }
        out[(b0 + bb) * 4 + o] = acc;
    }
}

extern "C" void kernel_launch(void* const* d_in, const int* in_sizes, int n_in,
                              void* d_out, int out_size, void* d_ws, size_t ws_size,
                              hipStream_t stream) {
    const float* x     = (const float*)d_in[0];
    const float* w_ih0 = (const float*)d_in[1];
    const float* w_hh0 = (const float*)d_in[2];
    const float* b_ih0 = (const float*)d_in[3];
    const float* b_hh0 = (const float*)d_in[4];
    const float* w_ih1 = (const float*)d_in[5];
    const float* w_hh1 = (const float*)d_in[6];
    const float* b_ih1 = (const float*)d_in[7];
    const float* b_hh1 = (const float*)d_in[8];
    const float* w_ih2 = (const float*)d_in[9];
    const float* w_hh2 = (const float*)d_in[10];
    const float* b_ih2 = (const float*)d_in[11];
    const float* b_hh2 = (const float*)d_in[12];
    const float* w_lin = (const float*)d_in[13];
    const float* b_lin = (const float*)d_in[14];

    lstm3_v16<<<dim3(256), dim3(768), 0, stream>>>(
        x, w_ih0, w_hh0, b_ih0, b_hh0,
        w_ih1, w_hh1, b_ih1, b_hh1,
        w_ih2, w_hh2, b_ih2, b_hh2,
        w_lin, b_lin, (float*)d_out);
}

// Round 17
// 295.167 us; speedup vs baseline: 1.0944x; 1.0944x over previous
//
#include <hip/hip_runtime.h>

// 3-layer LSTM (B=1024, T=512, H=64), f16 MFMA, fp32 cell state.
// grid = 256 blocks x 4 batches; 768 threads = 12 waves = 3 layer-teams x 4.
// R17 = R14 verbatim (measured champion, 295.7us): R6 lockstep skeleton +
// weights/biases pre-scaled by -log2e (g: -2log2e).
// Eleven variants measured worse (free-run sync x2, lgkm-only barrier,
// role-stagger, exp2-interleave, single-chain VALU diet, quad-rcp,
// 2 blocks/CU): the wall is the serialized MFMA+VALU issue/latency chain of
// the lockstep schedule -- at its measured source-level ceiling.
//
// Team L computes layer L at t = s - L (skewed pipeline), ONE barrier/step.
// A-frag reads use slot = l15>>2 (4-way same-address broadcast) so
// acc[tt][0] on lane (l4,l15) IS the preact of cell (batch=l4, unit=w*16+l15).
// mfma_f32_16x16x32_f16: A row = lane&15, k-chunk = lane>>4; D col = lane&15,
// D row = (lane>>4)*4+reg -- layout verified R2-R16.

typedef __attribute__((ext_vector_type(8))) _Float16 half8;
typedef __attribute__((ext_vector_type(4))) _Float16 half4;
typedef __attribute__((ext_vector_type(4))) float floatx4;

static constexpr int T_STEPS = 512;

#define NL2E  (-1.4426950408889634f)   // -log2(e)
#define N2L2E (-2.8853900817779268f)   // -2*log2(e)

// LDS: "cr" rows of 256B = [16 slots][16B]; slot ^= (cr&1)<<2.
// CR_X  : [2 buf][4 chunks]  (x frags, k=0..31, 24 real + 8 zero pad)
// CR_Hl : [2 buf][8 chunks]  (h frags, 64 units); slots 0..3 = batches.
#define CR_X   0
#define CR_H0  8
#define CR_H1  24
#define CR_H2  40
#define CR_TOT 56
#define SM_BYTES (CR_TOT * 256)        // 14336 B

__device__ __forceinline__ int lds_off(int cr, int slot) {
    return (cr * 16 + (slot ^ ((cr & 1) << 2))) * 16;
}

__device__ __forceinline__ floatx4 mfma16(half8 a, half8 b, floatx4 c) {
    return __builtin_amdgcn_mfma_f32_16x16x32_f16(a, b, c, 0, 0, 0);
}

__device__ __forceinline__ half8 cvt8s(const float* src, float s) {
    float4 v0 = *(const float4*)(src);
    float4 v1 = *(const float4*)(src + 4);
    half8 h;
    h[0] = (_Float16)(v0.x * s); h[1] = (_Float16)(v0.y * s);
    h[2] = (_Float16)(v0.z * s); h[3] = (_Float16)(v0.w * s);
    h[4] = (_Float16)(v1.x * s); h[5] = (_Float16)(v1.y * s);
    h[6] = (_Float16)(v1.z * s); h[7] = (_Float16)(v1.w * s);
    return h;
}

__global__ __launch_bounds__(768, 3) void lstm3_v17(
    const float* __restrict__ x,
    const float* __restrict__ w_ih0, const float* __restrict__ w_hh0,
    const float* __restrict__ b_ih0, const float* __restrict__ b_hh0,
    const float* __restrict__ w_ih1, const float* __restrict__ w_hh1,
    const float* __restrict__ b_ih1, const float* __restrict__ b_hh1,
    const float* __restrict__ w_ih2, const float* __restrict__ w_hh2,
    const float* __restrict__ b_ih2, const float* __restrict__ b_hh2,
    const float* __restrict__ w_lin, const float* __restrict__ b_lin,
    float* __restrict__ out)
{
    __shared__ __align__(16) char sm[SM_BYTES];

    const int tid  = threadIdx.x;
    const int lane = tid & 63;
    const int wave = tid >> 6;       // 0..11
    const int L    = wave >> 2;      // layer team 0..2
    const int w    = wave & 3;       // unit group within team
    const int l15  = lane & 15;
    const int l4   = lane >> 4;      // = this lane's BATCH
    const int b0   = blockIdx.x * 4; // global batch base (4 per block)
    const int u    = w * 16 + l15;   // this lane's hidden unit
    const int sl   = l15 >> 2;       // broadcast A slot

    // ---- zero x + h frag regions ----
    for (int i = tid; i < CR_TOT * 16; i += 768)
        *(floatx4*)(&sm[i * 16]) = floatx4{0.f, 0.f, 0.f, 0.f};

    // ---- per-team parameter pointers ----
    const float* wi = (L == 0) ? w_ih0 : (L == 1 ? w_ih1 : w_ih2);
    const float* wh = (L == 0) ? w_hh0 : (L == 1 ? w_hh1 : w_hh2);
    const float* bi = (L == 0) ? b_ih0 : (L == 1 ? b_ih1 : b_ih2);
    const float* bh = (L == 0) ? b_hh0 : (L == 1 ? b_hh1 : b_hh2);
    const int hbase = (L == 0) ? CR_H0 : (L == 1 ? CR_H1 : CR_H2);
    const int pbase = (L == 0) ? CR_X  : (L == 1 ? CR_H0 : CR_H1);

    // ---- register-resident B frags (weights), PRE-SCALED by -log2e ----
    half8 wf[4][4];
#pragma unroll
    for (int tt = 0; tt < 4; ++tt) {
        const int g = tt * 64 + u;
        const float sc = (tt == 2) ? N2L2E : NL2E;
        if (L == 0) {
            half8 z;
#pragma unroll
            for (int j = 0; j < 8; ++j) z[j] = (_Float16)0.f;
            wf[tt][0] = (l4 < 3) ? cvt8s(w_ih0 + g * 24 + l4 * 8, sc) : z;
            wf[tt][1] = cvt8s(w_hh0 + g * 64 + l4 * 8, sc);
            wf[tt][2] = cvt8s(w_hh0 + g * 64 + 32 + l4 * 8, sc);
            wf[tt][3] = z;   // unused
        } else {
            wf[tt][0] = cvt8s(wi + g * 64 + l4 * 8, sc);
            wf[tt][1] = cvt8s(wi + g * 64 + 32 + l4 * 8, sc);
            wf[tt][2] = cvt8s(wh + g * 64 + l4 * 8, sc);
            wf[tt][3] = cvt8s(wh + g * 64 + 32 + l4 * 8, sc);
        }
    }

    // ---- pre-scaled bias as MFMA C-input (same for all 4 acc rows) ----
    floatx4 bv[4];
#pragma unroll
    for (int tt = 0; tt < 4; ++tt) {
        const float sc = (tt == 2) ? N2L2E : NL2E;
        float b = sc * (bi[tt * 64 + u] + bh[tt * 64 + u]);
        bv[tt][0] = b; bv[tt][1] = b; bv[tt][2] = b; bv[tt][3] = b;
    }
    float cst = 0.0f;    // fp32 cell state of (batch l4, unit u, layer L)

    // ---- precomputed LDS byte addresses, both parities ----
    int ra0[4], ra1[4];
    if (L == 0) {
        ra0[0] = lds_off(CR_X + 0 + l4, sl);
        ra0[1] = lds_off(CR_H0 + 8 + l4, sl);
        ra0[2] = lds_off(CR_H0 + 12 + l4, sl);
        ra0[3] = 0;
        ra1[0] = lds_off(CR_X + 4 + l4, sl);
        ra1[1] = lds_off(CR_H0 + 0 + l4, sl);
        ra1[2] = lds_off(CR_H0 + 4 + l4, sl);
        ra1[3] = 0;
    } else {
        ra0[0] = lds_off(pbase + 0 + l4, sl);
        ra0[1] = lds_off(pbase + 4 + l4, sl);
        ra0[2] = lds_off(hbase + 8 + l4, sl);
        ra0[3] = lds_off(hbase + 12 + l4, sl);
        ra1[0] = lds_off(pbase + 8 + l4, sl);
        ra1[1] = lds_off(pbase + 12 + l4, sl);
        ra1[2] = lds_off(hbase + 0 + l4, sl);
        ra1[3] = lds_off(hbase + 4 + l4, sl);
    }
    const int wr0 = lds_off(hbase + 0 + (u >> 3), l4) + (u & 7) * 2;
    const int wr1 = lds_off(hbase + 8 + (u >> 3), l4) + (u & 7) * 2;

    // parity selects (loop-invariant, hoisted): even-s body has par = L&1
    const int Lodd = L & 1;
    const int eA0 = Lodd ? ra1[0] : ra0[0], eA1 = Lodd ? ra1[1] : ra0[1];
    const int eA2 = Lodd ? ra1[2] : ra0[2], eA3 = Lodd ? ra1[3] : ra0[3];
    const int oA0 = Lodd ? ra0[0] : ra1[0], oA1 = Lodd ? ra0[1] : ra1[1];
    const int oA2 = Lodd ? ra0[2] : ra1[2], oA3 = Lodd ? ra0[3] : ra1[3];
    const int eWr = Lodd ? wr1 : wr0, oWr = Lodd ? wr0 : wr1;

    // ---- x staging: thread tid<24 owns (batch xb, float4 xf) ----
    const int xb = tid / 6, xf = tid % 6;
    const int xw0 = lds_off(CR_X + 0 + (xf >> 1), xb) + (xf & 1) * 8;
    const int xw1 = lds_off(CR_X + 4 + (xf >> 1), xb) + (xf & 1) * 8;
    const float* xg = x + ((long)(b0 + xb) * T_STEPS + 1) * 24 + xf * 4;
    if (tid < 24) {
        float4 v = *(const float4*)(x + ((long)(b0 + xb) * T_STEPS + 0) * 24 + xf * 4);
        half4 hv; hv[0] = (_Float16)v.x; hv[1] = (_Float16)v.y;
                  hv[2] = (_Float16)v.z; hv[3] = (_Float16)v.w;
        *(half4*)(&sm[xw0]) = hv;
    }
    __syncthreads();

    auto body = [&](int s, int A0, int A1, int A2, int A3, int WR, int XW) {
        const int t = s - L;
        const bool active = ((unsigned)t < (unsigned)T_STEPS);
        float4 xpre;
        const bool do_x = (tid < 24) && (s + 1 < T_STEPS);
        if (do_x) xpre = *(const float4*)xg;

        if (active) {
            floatx4 acc[4];
            __builtin_amdgcn_s_setprio(1);
            if (L == 0) {
                half8 aX  = *(const half8*)(&sm[A0]);
                half8 aP0 = *(const half8*)(&sm[A1]);
                half8 aP1 = *(const half8*)(&sm[A2]);
#pragma unroll
                for (int tt = 0; tt < 4; ++tt) {
                    acc[tt] = mfma16(aX,  wf[tt][0], bv[tt]);
                    acc[tt] = mfma16(aP0, wf[tt][1], acc[tt]);
                    acc[tt] = mfma16(aP1, wf[tt][2], acc[tt]);
                }
            } else {
                half8 aI0 = *(const half8*)(&sm[A0]);
                half8 aI1 = *(const half8*)(&sm[A1]);
                half8 aO0 = *(const half8*)(&sm[A2]);
                half8 aO1 = *(const half8*)(&sm[A3]);
#pragma unroll
                for (int tt = 0; tt < 4; ++tt) {
                    acc[tt] = mfma16(aI0, wf[tt][0], bv[tt]);
                    acc[tt] = mfma16(aI1, wf[tt][1], acc[tt]);
                    acc[tt] = mfma16(aO0, wf[tt][2], acc[tt]);
                    acc[tt] = mfma16(aO1, wf[tt][3], acc[tt]);
                }
            }
            __builtin_amdgcn_s_setprio(0);

            // activation: 1 cell/lane; acc = -(preact)*log2e (g: -2log2e)
            float ei = __builtin_amdgcn_exp2f(acc[0][0]);
            float ef = __builtin_amdgcn_exp2f(acc[1][0]);
            float eg = __builtin_amdgcn_exp2f(acc[2][0]);
            float eo = __builtin_amdgcn_exp2f(acc[3][0]);
            float ig = __builtin_amdgcn_rcpf(1.f + ei);
            float fg = __builtin_amdgcn_rcpf(1.f + ef);
            float sg = __builtin_amdgcn_rcpf(1.f + eg);
            float og = __builtin_amdgcn_rcpf(1.f + eo);
            float gg = fmaf(2.f, sg, -1.f);                 // tanh(g)
            cst = fmaf(fg, cst, ig * gg);
            float et = __builtin_amdgcn_exp2f(cst * N2L2E);
            float th = fmaf(2.f, __builtin_amdgcn_rcpf(1.f + et), -1.f);
            float hv = og * th;
            *(_Float16*)(&sm[WR]) = (_Float16)hv;
        }
        if (do_x) {
            half4 hv; hv[0] = (_Float16)xpre.x; hv[1] = (_Float16)xpre.y;
                      hv[2] = (_Float16)xpre.z; hv[3] = (_Float16)xpre.w;
            *(half4*)(&sm[XW]) = hv;
        }
        xg += 24;
        __syncthreads();
    };

    for (int s = 0; s < T_STEPS + 2; s += 2) {
        body(s,     eA0, eA1, eA2, eA3, eWr, xw1);   // writes x(s+1) -> buf 1
        body(s + 1, oA0, oA1, oA2, oA3, oWr, xw0);   // writes x(s+2) -> buf 0
    }

    // ---- final linear: out[b,o] = h2(511) . w_lin[o,:] + b_lin[o] ----
    if (tid < 16) {
        const int bb = tid >> 2, o = tid & 3;
        const int hb = CR_H2 + ((T_STEPS - 1) & 1) * 8;
        float acc = b_lin[o];
#pragma unroll
        for (int k = 0; k < 64; ++k) {
            _Float16 hv = *(const _Float16*)(&sm[lds_off(hb + (k >> 3), bb) + (k & 7) * 2]);
            acc = fmaf((float)hv, w_lin[o * 64 + k], acc);
        }
        out[(b0 + bb) * 4 + o] = acc;
    }
}

extern "C" void kernel_launch(void* const* d_in, const int* in_sizes, int n_in,
                              void* d_out, int out_size, void* d_ws, size_t ws_size,
                              hipStream_t stream) {
    const float* x     = (const float*)d_in[0];
    const float* w_ih0 = (const float*)d_in[1];
    const float* w_hh0 = (const float*)d_in[2];
    const float* b_ih0 = (const float*)d_in[3];
    const float* b_hh0 = (const float*)d_in[4];
    const float* w_ih1 = (const float*)d_in[5];
    const float* w_hh1 = (const float*)d_in[6];
    const float* b_ih1 = (const float*)d_in[7];
    const float* b_hh1 = (const float*)d_in[8];
    const float* w_ih2 = (const float*)d_in[9];
    const float* w_hh2 = (const float*)d_in[10];
    const float* b_ih2 = (const float*)d_in[11];
    const float* b_hh2 = (const float*)d_in[12];
    const float* w_lin = (const float*)d_in[13];
    const float* b_lin = (const float*)d_in[14];

    lstm3_v17<<<dim3(256), dim3(768), 0, stream>>>(
        x, w_ih0, w_hh0, b_ih0, b_hh0,
        w_ih1, w_hh1, b_ih1, b_hh1,
        w_ih2, w_hh2, b_ih2, b_hh2,
        w_lin, b_lin, (float*)d_out);
}